// Round 2
// baseline (3613.120 us; speedup 1.0000x reference)
//
#include <hip/hip_runtime.h>
#include <cstdint>

#define TT 128
#define BB 128
#define HH 512

typedef _Float16 f16;
typedef _Float16 f16x8 __attribute__((ext_vector_type(8)));
typedef float f32x4 __attribute__((ext_vector_type(4)));
typedef unsigned int u32;

// ---- workspace layout (bytes) ----
#define OFF_H0    4096                  // enc layer0 h, [2][128][512] f16 (swizzled rows)
#define OFF_H1    (OFF_H0 + 262144)     // enc layer1 h
#define OFF_D0    (OFF_H1 + 262144)     // dec layer0 h
#define OFF_D1    (OFF_D0 + 262144)     // dec layer1 h
#define OFF_XH    (OFF_D1 + 262144)     // x as f16, [T][128][64], row-swizzled
#define OFF_HS    (OFF_XH + 2097152)    // decoder outputs [T][128][512] f16 (plain)

// ---- LDS layout (bytes) ----
#define L_FC   0          // [64][512] f16 fcW (epilogue only)
#define L_P0   65536      // [32][36] f32 gate preacts layer0 (stride 36: conflict-free)
#define L_P1   70144      // [32][36] f32 gate preacts layer1
#define L_B0   74752      // 32 f32 bias layer0
#define L_B1   74880      // 32 f32 bias layer1
#define L_TOT  75008

#define MFMA16(a,b,c) __builtin_amdgcn_mfma_f32_16x16x32_f16((a),(b),(c),0,0,0)

__device__ __forceinline__ float sigm(float x){ return 1.f/(1.f+__expf(-x)); }
__device__ __forceinline__ float tanhft(float x){ return 1.f - 2.f/(__expf(2.f*x)+1.f); }

// load one B-fragment (8 f16 along K for gate-row srow) from an fp32 weight matrix
__device__ __forceinline__ f16x8 wfrag(const float* __restrict__ src, int K, int srow,
                                       int k, int l8){
  const float* p = src + srow*K + (k<<5) + (l8<<3);
  float4 v0 = *(const float4*)p;
  float4 v1 = *(const float4*)(p+4);
  f16x8 r;
  r[0]=(f16)v0.x; r[1]=(f16)v0.y; r[2]=(f16)v0.z; r[3]=(f16)v0.w;
  r[4]=(f16)v1.x; r[5]=(f16)v1.y; r[6]=(f16)v1.z; r[7]=(f16)v1.w;
  return r;
}

// group-local (64 WG) barrier: publish flag, wave0 polls the 64-flag array
// (one coalesced 256B agent load per iteration), then release + acquire fence.
__device__ __forceinline__ void gbar(int* fl, int cg, int tid, int target){
  __syncthreads();   // drains vmcnt(0): all agent-scope h stores at coherence point
  if (tid == 0)
    __hip_atomic_store(&fl[cg], target, __ATOMIC_RELAXED, __HIP_MEMORY_SCOPE_AGENT);
  if (tid < 64){
    bool ok;
    do {
      ok = __hip_atomic_load(&fl[tid], __ATOMIC_RELAXED, __HIP_MEMORY_SCOPE_AGENT) >= target;
    } while (!__all(ok));
  }
  __syncthreads();
  __builtin_amdgcn_fence(__ATOMIC_ACQUIRE, "agent");  // invalidate stale L1/L2 before reading peers' h
}

// convert x [B][T][64] f32 -> xh [T][128][64] f16, rows XOR-swizzled in 16B blocks
__global__ void cvt_x(const float* __restrict__ x, char* __restrict__ ws){
  int idx = blockIdx.x*256 + threadIdx.x;        // 131072 = T*B*8 units of 16B
  int t = idx >> 10, rem = idx & 1023, b = rem >> 3, blk = rem & 7;
  const float* s = x + (((b<<7) + t)<<6) + (blk<<3);
  float4 v0 = *(const float4*)s, v1 = *(const float4*)(s+4);
  f16x8 h;
  h[0]=(f16)v0.x; h[1]=(f16)v0.y; h[2]=(f16)v0.z; h[3]=(f16)v0.w;
  h[4]=(f16)v1.x; h[5]=(f16)v1.y; h[6]=(f16)v1.z; h[7]=(f16)v1.w;
  int db = blk ^ (b & 7);
  *(f16x8*)(ws + OFF_XH + (((t<<7)+b)<<7) + (db<<4)) = h;
}

__global__ __launch_bounds__(256, 1) void lstm_persist(
    const float* __restrict__ eWih0, const float* __restrict__ eWhh0,
    const float* __restrict__ ebi0,  const float* __restrict__ ebh0,
    const float* __restrict__ eWih1, const float* __restrict__ eWhh1,
    const float* __restrict__ ebi1,  const float* __restrict__ ebh1,
    const float* __restrict__ dWih0, const float* __restrict__ dWhh0,
    const float* __restrict__ dbi0,  const float* __restrict__ dbh0,
    const float* __restrict__ dWih1, const float* __restrict__ dWhh1,
    const float* __restrict__ dbi1,  const float* __restrict__ dbh1,
    const float* __restrict__ fcW,   const float* __restrict__ fcb,
    float* __restrict__ out, char* __restrict__ ws)
{
  __shared__ __align__(16) char lds[L_TOT];
  const int tid  = threadIdx.x;
  const int wg   = blockIdx.x;
  const int g    = wg >> 6;            // batch group (32 rows) - groups independent
  const int cg   = wg & 63;            // column group (8 h-cols = 32 gate-cols)
  const int b0   = g << 5;
  const int lane = tid & 63, wave = tid >> 6;
  const int mi = wave >> 1, ni = wave & 1;       // wave -> 16x16 C tile (2x2)
  const int arow = (mi<<4) + (lane & 15);        // A frag row (batch row in group)
  const int l8   = lane >> 4;                    // which 8-elem k-run (0..3)
  const int klb  = l8 << 4;                      // its byte offset in a 32k chunk
  const int brow = (ni<<4) + (lane & 15);        // B frag row (gate col in WG slice)
  const int srow = ((brow>>3)<<9) + (cg<<3) + (brow&7);  // global gate row
  const int sw   = (arow & 7) << 4;              // row XOR-swizzle for A loads
  const int pcol = brow;
  const int rb = tid >> 3, hcl = tid & 7;        // gate phase: thread = (row, h-col)

  int* flags = (int*)ws + (g<<6);
  char* H0 = ws + OFF_H0;  char* H1 = ws + OFF_H1;
  char* D0 = ws + OFF_D0;  char* D1 = ws + OFF_D1;
  const char* XH = ws + OFF_XH;
  char* HS = ws + OFF_HS;

  float* P0 = (float*)(lds + L_P0); float* P1 = (float*)(lds + L_P1);
  float* B0 = (float*)(lds + L_B0); float* B1 = (float*)(lds + L_B1);

  // per-k swizzled A byte offsets (loop-invariant)
  int o16[16];
#pragma unroll
  for (int k = 0; k < 16; ++k) o16[k] = ((k<<6) + klb) ^ sw;
  const int ox0 = klb ^ sw, ox1 = (64 + klb) ^ sw;

  // ---- encoder weights -> registers (loop-invariant fragments) ----
  f16x8 wA[16], wB[16], wC[16], wX0, wX1;
#pragma unroll
  for (int k = 0; k < 16; ++k){
    wA[k] = wfrag(eWhh0, 512, srow, k, l8);
    wB[k] = wfrag(eWih1, 512, srow, k, l8);
    wC[k] = wfrag(eWhh1, 512, srow, k, l8);
  }
  wX0 = wfrag(eWih0, 64, srow, 0, l8);
  wX1 = wfrag(eWih0, 64, srow, 1, l8);
  if (tid < 32){
    int sr = ((tid>>3)<<9) + (cg<<3) + (tid&7);
    B0[tid] = ebi0[sr] + ebh0[sr];
    B1[tid] = ebi1[sr] + ebh1[sr];
  }
  __syncthreads();

  float c0v = 0.f, c1v = 0.f;
  int bt = 0;

  // ================= encoder: layers 0+1 pipelined, 1 barrier/step =================
  for (int s = 0; s <= TT; ++s){
    const bool d0 = (s < TT), d1 = (s >= 1);
    const char* r0row = H0 + ((s&1)<<17) + ((b0 + arow)<<10);
    const char* r1row = H1 + ((s&1)<<17) + ((b0 + arow)<<10);
    char* W0 = H0 + (((s+1)&1)<<17) + (b0<<10);
    char* W1 = H1 + (((s+1)&1)<<17) + (b0<<10);

    // issue all A loads up-front (global -> VGPR, one exposed latency)
    f16x8 xa0, xa1;
    if (d0){
      const char* xrow = XH + (((s<<7) + b0 + arow)<<7);
      xa0 = *(const f16x8*)(xrow + ox0);
      xa1 = *(const f16x8*)(xrow + ox1);
    }
    f16x8 a0f[16], a1f[16];
#pragma unroll
    for (int k = 0; k < 16; ++k){
      a0f[k] = *(const f16x8*)(r0row + o16[k]);
      a1f[k] = *(const f16x8*)(r1row + o16[k]);
    }

    f32x4 acc0 = {0.f,0.f,0.f,0.f}, acc1 = {0.f,0.f,0.f,0.f};
    if (d0){
      acc0 = MFMA16(xa0, wX0, acc0);
      acc0 = MFMA16(xa1, wX1, acc0);
    }
#pragma unroll
    for (int k = 0; k < 16; ++k){
      acc0 = MFMA16(a0f[k], wA[k], acc0);       // h0[t-1] serves BOTH layers
      acc1 = MFMA16(a0f[k], wB[k], acc1);
      acc1 = MFMA16(a1f[k], wC[k], acc1);
    }

#pragma unroll
    for (int r = 0; r < 4; ++r){               // C layout: col=lane&15, row=(lane>>4)*4+r
      int prow = (mi<<4) + (l8<<2) + r;
      P0[prow*36 + pcol] = acc0[r];
      P1[prow*36 + pcol] = acc1[r];
    }
    __syncthreads();

    if (d0){
      float gi = sigm  (P0[rb*36 +      hcl] + B0[hcl]);
      float gf = sigm  (P0[rb*36 +  8 + hcl] + B0[8+hcl]);
      float gg = tanhft(P0[rb*36 + 16 + hcl] + B0[16+hcl]);
      float go = sigm  (P0[rb*36 + 24 + hcl] + B0[24+hcl]);
      c0v = gf*c0v + gi*gg;
      float h = go * tanhft(c0v);
      union { f16 hf; unsigned short su; } cv; cv.hf = (f16)h;
      u32 other = (u32)__shfl_xor((int)(u32)cv.su, 1, 64);
      if (!(hcl & 1)){
        u32 pk = (u32)cv.su | (other << 16);
        int blk = cg ^ (rb & 7);
        __hip_atomic_store((u32*)(W0 + (rb<<10) + (blk<<4) + (hcl<<1)), pk,
                           __ATOMIC_RELAXED, __HIP_MEMORY_SCOPE_AGENT);
      }
    }
    if (d1){
      float gi = sigm  (P1[rb*36 +      hcl] + B1[hcl]);
      float gf = sigm  (P1[rb*36 +  8 + hcl] + B1[8+hcl]);
      float gg = tanhft(P1[rb*36 + 16 + hcl] + B1[16+hcl]);
      float go = sigm  (P1[rb*36 + 24 + hcl] + B1[24+hcl]);
      c1v = gf*c1v + gi*gg;
      float h = go * tanhft(c1v);
      union { f16 hf; unsigned short su; } cv; cv.hf = (f16)h;
      u32 other = (u32)__shfl_xor((int)(u32)cv.su, 1, 64);
      if (!(hcl & 1)){
        u32 pk = (u32)cv.su | (other << 16);
        int blk = cg ^ (rb & 7);
        __hip_atomic_store((u32*)(W1 + (rb<<10) + (blk<<4) + (hcl<<1)), pk,
                           __ATOMIC_RELAXED, __HIP_MEMORY_SCOPE_AGENT);
      }
    }
    gbar(flags, cg, tid, ++bt);
  }

  // ================= zx = z @ dW_ih0 + biases (one-time, kept in regs) =================
#pragma unroll
  for (int k = 0; k < 16; ++k) wB[k] = wfrag(dWih0, 512, srow, k, l8);  // reuse wB
  f32x4 zx;
  {
    float zb = dbi0[srow] + dbh0[srow];
    zx[0]=zb; zx[1]=zb; zx[2]=zb; zx[3]=zb;
  }
  {
    const char* zrow = H1 + (1<<17) + ((b0 + arow)<<10);  // z = final enc1 h, parity 1
#pragma unroll
    for (int k = 0; k < 16; ++k){
      f16x8 zf = *(const f16x8*)(zrow + o16[k]);
      zx = MFMA16(zf, wB[k], zx);
    }
  }

  // ---- decoder weights -> registers ----
#pragma unroll
  for (int k = 0; k < 16; ++k){
    wA[k] = wfrag(dWhh0, 512, srow, k, l8);
    wB[k] = wfrag(dWih1, 512, srow, k, l8);
    wC[k] = wfrag(dWhh1, 512, srow, k, l8);
  }
  if (tid < 32){
    int sr = ((tid>>3)<<9) + (cg<<3) + (tid&7);
    B1[tid] = dbi1[sr] + dbh1[sr];
  }
  __syncthreads();
  c0v = 0.f; c1v = 0.f;

  // ================= decoder: layers 0+1 pipelined =================
  for (int s = 0; s <= TT; ++s){
    const bool d0 = (s < TT), d1 = (s >= 1);
    const char* r0row = D0 + ((s&1)<<17) + ((b0 + arow)<<10);
    const char* r1row = D1 + ((s&1)<<17) + ((b0 + arow)<<10);
    char* W0 = D0 + (((s+1)&1)<<17) + (b0<<10);
    char* W1 = D1 + (((s+1)&1)<<17) + (b0<<10);

    f16x8 a0f[16], a1f[16];
#pragma unroll
    for (int k = 0; k < 16; ++k){
      a0f[k] = *(const f16x8*)(r0row + o16[k]);
      a1f[k] = *(const f16x8*)(r1row + o16[k]);
    }

    f32x4 acc0 = zx, acc1 = {0.f,0.f,0.f,0.f};  // constant-z product + biases preloaded
#pragma unroll
    for (int k = 0; k < 16; ++k){
      acc0 = MFMA16(a0f[k], wA[k], acc0);
      acc1 = MFMA16(a0f[k], wB[k], acc1);
      acc1 = MFMA16(a1f[k], wC[k], acc1);
    }

#pragma unroll
    for (int r = 0; r < 4; ++r){
      int prow = (mi<<4) + (l8<<2) + r;
      P0[prow*36 + pcol] = acc0[r];
      P1[prow*36 + pcol] = acc1[r];
    }
    __syncthreads();

    if (d0){
      float gi = sigm  (P0[rb*36 +      hcl]);   // biases already inside zx
      float gf = sigm  (P0[rb*36 +  8 + hcl]);
      float gg = tanhft(P0[rb*36 + 16 + hcl]);
      float go = sigm  (P0[rb*36 + 24 + hcl]);
      c0v = gf*c0v + gi*gg;
      float h = go * tanhft(c0v);
      union { f16 hf; unsigned short su; } cv; cv.hf = (f16)h;
      u32 other = (u32)__shfl_xor((int)(u32)cv.su, 1, 64);
      if (!(hcl & 1)){
        u32 pk = (u32)cv.su | (other << 16);
        int blk = cg ^ (rb & 7);
        __hip_atomic_store((u32*)(W0 + (rb<<10) + (blk<<4) + (hcl<<1)), pk,
                           __ATOMIC_RELAXED, __HIP_MEMORY_SCOPE_AGENT);
      }
    }
    if (d1){
      float gi = sigm  (P1[rb*36 +      hcl] + B1[hcl]);
      float gf = sigm  (P1[rb*36 +  8 + hcl] + B1[8+hcl]);
      float gg = tanhft(P1[rb*36 + 16 + hcl] + B1[16+hcl]);
      float go = sigm  (P1[rb*36 + 24 + hcl] + B1[24+hcl]);
      c1v = gf*c1v + gi*gg;
      float h = go * tanhft(c1v);
      union { f16 hf; unsigned short su; } cv; cv.hf = (f16)h;
      u32 other = (u32)__shfl_xor((int)(u32)cv.su, 1, 64);
      if (!(hcl & 1)){
        u32 pk = (u32)cv.su | (other << 16);
        int blk = cg ^ (rb & 7);
        __hip_atomic_store((u32*)(W1 + (rb<<10) + (blk<<4) + (hcl<<1)), pk,
                           __ATOMIC_RELAXED, __HIP_MEMORY_SCOPE_AGENT);
        // plain-layout copy for fc
        __hip_atomic_store((u32*)(HS + ((((s-1)<<7) + b0 + rb)<<10) + (cg<<4) + (hcl<<1)), pk,
                           __ATOMIC_RELAXED, __HIP_MEMORY_SCOPE_AGENT);
      }
    }
    gbar(flags, cg, tid, ++bt);
  }

  // ================= fc: out[b][t][:] = HS[t][b][:] @ fcW^T + fcb (group-local) =================
  for (int q = tid; q < 8192; q += 256){        // stage fcW [64][512] -> f16 LDS
    int i = q >> 7, kq = q & 127;
    float4 v = *(const float4*)(fcW + (i<<9) + (kq<<2));
    f16* p = (f16*)(lds + L_FC + (i<<10) + (kq<<3));
    p[0]=(f16)v.x; p[1]=(f16)v.y; p[2]=(f16)v.z; p[3]=(f16)v.w;
  }
  __syncthreads();
  {
    int tl = tid >> 7;
    int t  = (cg<<1) + tl;                      // 64 col-groups x 2 = all 128 timesteps
    int r  = (tid>>2) & 31;
    int iq = tid & 3;
    const char* hsrow = HS + (((t<<7) + b0 + r)<<10);
    float acc[16];
#pragma unroll
    for (int ii = 0; ii < 16; ++ii) acc[ii] = 0.f;
    for (int k8 = 0; k8 < 64; ++k8){
      f16x8 hv = *(const f16x8*)(hsrow + (k8<<4));
#pragma unroll
      for (int ii = 0; ii < 16; ++ii){
        f16x8 wv = *(const f16x8*)(lds + L_FC + (((iq<<4)+ii)<<10) + (k8<<4));
#pragma unroll
        for (int j = 0; j < 8; ++j) acc[ii] += (float)hv[j] * (float)wv[j];
      }
    }
#pragma unroll
    for (int ii = 0; ii < 16; ++ii){
      int i = (iq<<4) + ii;
      out[((((b0+r)<<7) + t)<<6) + i] = acc[ii] + fcb[i];
    }
  }
}

extern "C" void kernel_launch(void* const* d_in, const int* in_sizes, int n_in,
                              void* d_out, int out_size, void* d_ws, size_t ws_size,
                              hipStream_t stream){
  const float* x     = (const float*)d_in[0];
  const float* eWih0 = (const float*)d_in[1];
  const float* eWhh0 = (const float*)d_in[2];
  const float* ebi0  = (const float*)d_in[3];
  const float* ebh0  = (const float*)d_in[4];
  const float* eWih1 = (const float*)d_in[5];
  const float* eWhh1 = (const float*)d_in[6];
  const float* ebi1  = (const float*)d_in[7];
  const float* ebh1  = (const float*)d_in[8];
  const float* dWih0 = (const float*)d_in[9];
  const float* dWhh0 = (const float*)d_in[10];
  const float* dbi0  = (const float*)d_in[11];
  const float* dbh0  = (const float*)d_in[12];
  const float* dWih1 = (const float*)d_in[13];
  const float* dWhh1 = (const float*)d_in[14];
  const float* dbi1  = (const float*)d_in[15];
  const float* dbh1  = (const float*)d_in[16];
  const float* fcW   = (const float*)d_in[17];
  const float* fcb   = (const float*)d_in[18];
  char* ws = (char*)d_ws;

  hipMemsetAsync(d_ws, 0, OFF_XH, stream);       // zero barrier flags + all h double-buffers
  cvt_x<<<512, 256, 0, stream>>>(x, ws);
  lstm_persist<<<256, 256, 0, stream>>>(eWih0,eWhh0,ebi0,ebh0,eWih1,eWhh1,ebi1,ebh1,
                                        dWih0,dWhh0,dbi0,dbh0,dWih1,dWhh1,dbi1,dbh1,
                                        fcW,fcb,(float*)d_out,ws);
}